// Round 3
// baseline (562.439 us; speedup 1.0000x reference)
//
#include <hip/hip_runtime.h>
#include <hip/hip_bf16.h>
#include <math.h>

// Problem constants (from reference setup_inputs)
#define NNODES 100000
#define F_IN   500
#define F_MID  64
#define F_OUT  40
#define KPAD   512     // F_IN padded to multiple of 32 for MFMA
#define H2S    48      // h2 row stride (40 classes + 8 zero pad cols)

// Bucketed CSR build: 128 nodes per bucket
#define BSH    7
#define NBUCK  782     // ceil(100000 / 128)
#define EPB    8192    // edges per block in bucket kernels
#define K4CACHE 3072   // LDS edge cache per bucket (mean 2046, +20 sigma)

typedef __attribute__((ext_vector_type(8))) short short8;   // 8 bf16 = 4 VGPRs
typedef __attribute__((ext_vector_type(4))) float f32x4;    // MFMA acc

__device__ __forceinline__ unsigned short f2bf(float f) {
    union { float f; unsigned u; } c; c.f = f;
    unsigned r = c.u + 0x7FFF + ((c.u >> 16) & 1);   // round-nearest-even
    return (unsigned short)(r >> 16);
}
__device__ __forceinline__ float bf2f(unsigned short u) {
    union { unsigned v; float f; } c; c.v = ((unsigned)u) << 16; return c.f;
}

// ---------------------------------------------------------------------------
// CSR build, two-level bucket sort. All per-edge atomics are LDS-local;
// device atomics only per (tile,bucket) reservation (~150k non-hot).
// ---------------------------------------------------------------------------

// K1: per-bucket edge counts. LDS histogram, one device atomic per
// (block,bucket) with nonzero count.
__global__ __launch_bounds__(256) void bucket_count(const int* __restrict__ dst,
                                                    int* __restrict__ bcnt, int E) {
    __shared__ int h[NBUCK];
    int tid = threadIdx.x;
    for (int b = tid; b < NBUCK; b += 256) h[b] = 0;
    __syncthreads();
    int base = blockIdx.x * EPB;
#pragma unroll
    for (int j = 0; j < EPB / 256; j++) {
        int e = base + j * 256 + tid;
        if (e < E) atomicAdd(&h[dst[e] >> BSH], 1);
    }
    __syncthreads();
    for (int b = tid; b < NBUCK; b += 256) {
        int c = h[b];
        if (c) atomicAdd(&bcnt[b], c);
    }
}

// K2: exclusive scan of the 782 bucket counts (single block).
__global__ __launch_bounds__(1024) void bucket_scan(const int* __restrict__ bcnt,
                                                    int* __restrict__ bstart,
                                                    int* __restrict__ bcur, int E) {
    __shared__ int wsum[16];
    int t = threadIdx.x, lane = t & 63, w = t >> 6;
    int v = (t < NBUCK) ? bcnt[t] : 0;
    int s = v;
#pragma unroll
    for (int off = 1; off < 64; off <<= 1) {
        int u = __shfl_up(s, off, 64);
        if (lane >= off) s += u;
    }
    if (lane == 63) wsum[w] = s;
    __syncthreads();
    if (w == 0) {
        int ws = (lane < 16) ? wsum[lane] : 0;
#pragma unroll
        for (int off = 1; off < 16; off <<= 1) {
            int u = __shfl_up(ws, off, 64);
            if (lane >= off) ws += u;
        }
        if (lane < 16) wsum[lane] = ws;
    }
    __syncthreads();
    int excl = s - v + ((w > 0) ? wsum[w - 1] : 0);
    if (t < NBUCK) { bstart[t] = excl; bcur[t] = excl; }
    if (t == 0) bstart[NBUCK] = E;
}

// K3: scatter edges into bucket-contiguous staging. One returning device
// atomic per (block,bucket); per-edge ranks via LDS atomics. Payload packed
// as (local_node << 17) | src  (src < 2^17, local_node < 128).
__global__ __launch_bounds__(256) void bucket_scatter(const int* __restrict__ src,
                                                      const int* __restrict__ dst,
                                                      int* __restrict__ bcur,
                                                      int* __restrict__ stage, int E) {
    __shared__ int h[NBUCK];
    __shared__ int lcur[NBUCK];
    int tid = threadIdx.x;
    for (int b = tid; b < NBUCK; b += 256) h[b] = 0;
    __syncthreads();
    int base = blockIdx.x * EPB;
#pragma unroll
    for (int j = 0; j < EPB / 256; j++) {
        int e = base + j * 256 + tid;
        if (e < E) atomicAdd(&h[dst[e] >> BSH], 1);
    }
    __syncthreads();
    // Rotate flush order per block so concurrent blocks hit different
    // cache lines of bcur (reduces same-line atomic serialization).
    int rot = (blockIdx.x * 97) % NBUCK;
    for (int i = tid; i < NBUCK; i += 256) {
        int b = i + rot; if (b >= NBUCK) b -= NBUCK;
        int c = h[b];
        lcur[b] = c ? atomicAdd(&bcur[b], c) : 0;
    }
    __syncthreads();
#pragma unroll
    for (int j = 0; j < EPB / 256; j++) {
        int e = base + j * 256 + tid;
        if (e < E) {
            int d = dst[e];
            int pos = atomicAdd(&lcur[d >> BSH], 1);
            stage[pos] = ((d & 127) << 17) | src[e];
        }
    }
}

// K4: one block per bucket. LDS node histogram -> local scan (+1 self-loop
// per node) gives row_start analytically; LDS cursors scatter edges into a
// contiguous ~8.6KB csr window. Also writes dinv and self-loop entries.
__global__ __launch_bounds__(256) void bucket_fill(const int* __restrict__ stage,
                                                   const int* __restrict__ bstart,
                                                   int* __restrict__ row_start,
                                                   float* __restrict__ dinv,
                                                   int* __restrict__ csr_src, int E) {
    __shared__ int cnt[128];
    __shared__ int wtot[2];
    __shared__ int cache[K4CACHE];
    int tid = threadIdx.x;
    int b = blockIdx.x;
    int s0 = bstart[b], s1 = bstart[b + 1];
    int nE = s1 - s0;
    if (tid < 128) cnt[tid] = 0;
    __syncthreads();
    bool cached = (nE <= K4CACHE);
    for (int i = tid; i < nE; i += 256) {
        int v = stage[s0 + i];
        if (cached) cache[i] = v;
        atomicAdd(&cnt[v >> 17], 1);
    }
    __syncthreads();
    int n = (b << BSH) + tid;
    bool valid = (tid < 128) && (n < NNODES);
    int c = (tid < 128) ? cnt[tid] : 0;
    int add = valid ? (c + 1) : 0;        // +1 self-loop per valid node
    int s = add;
    int lane = tid & 63;
#pragma unroll
    for (int off = 1; off < 64; off <<= 1) {
        int u = __shfl_up(s, off, 64);
        if (lane >= off) s += u;
    }
    if (tid < 128 && lane == 63) wtot[tid >> 6] = s;
    __syncthreads();
    int excl = s - add + ((tid >= 64 && tid < 128) ? wtot[0] : 0);
    // edges before this bucket = s0; self-loops before = 128*b
    int basep = s0 + (b << BSH) + excl;
    if (valid) {
        row_start[n] = basep;
        dinv[n] = rsqrtf((float)(c + 1));
        csr_src[basep] = n;               // self-loop first
        cnt[tid] = basep + 1;             // reuse as global-position cursor
    }
    if (b == NBUCK - 1 && tid == 0) row_start[NNODES] = E + NNODES;
    __syncthreads();
    for (int i = tid; i < nE; i += 256) {
        int v = cached ? cache[i] : stage[s0 + i];
        int pos = atomicAdd(&cnt[v >> 17], 1);
        csr_src[pos] = v & 0x1FFFF;
    }
}

// ---------------------------------------------------------------------------
// W1 -> bf16, transposed, K padded: W1T[n][k], n<64, k<512
// ---------------------------------------------------------------------------
__global__ void w1t_prep(const float* __restrict__ W1, unsigned short* __restrict__ W1T) {
    int idx = blockIdx.x * blockDim.x + threadIdx.x;   // 64*512
    if (idx >= F_MID * KPAD) return;
    int n = idx >> 9;          // /512
    int k = idx & (KPAD - 1);
    float v = (k < F_IN) ? W1[k * F_MID + n] : 0.f;
    W1T[idx] = f2bf(v);
}

// W2 -> bf16, transposed, padded: W2T[col][k], col<48 (40 real), k<64
__global__ void w2t_prep(const float* __restrict__ W2, unsigned short* __restrict__ W2T) {
    int idx = blockIdx.x * blockDim.x + threadIdx.x;   // 48*64
    if (idx >= H2S * F_MID) return;
    int c = idx >> 6;
    int k = idx & 63;
    float v = (c < F_OUT) ? W2[k * F_OUT + c] : 0.f;
    W2T[idx] = f2bf(v);
}

// ---------------------------------------------------------------------------
// GEMM1 (bf16 MFMA): h1b = (X @ W1) * dinv[row]
// Key change vs prior rounds: X is read with CONTIGUOUS wave-long loads.
// Each wave owns 16 whole rows; lane l reads float4 at col 4l (64 lanes x
// 16B = 1KB = 8 sequential cache lines per instruction, 32 independent
// row-loads in flight) instead of the old 16-row strided gather that touched
// 16-32 scattered lines per instruction and exhausted L1 miss slots.
// Tile staged in LDS (64 rows x 512 bf16 = 64KB) with XOR swizzle
// (col_byte ^ ((row&7)<<4)) so the stride-1024 MFMA fragment reads are
// bank-conflict-free. One barrier total; B frags from L2-resident W1T.
// ---------------------------------------------------------------------------
__global__ __launch_bounds__(256, 2) void gemm1_kernel(const float* __restrict__ X,
                                                       const unsigned short* __restrict__ W1T,
                                                       const float* __restrict__ dinv,
                                                       unsigned short* __restrict__ h1b) {
    __shared__ __align__(16) unsigned short A_lds[64][KPAD];   // 64 KB, swizzled cols

    int tid = threadIdx.x;
    int wave = tid >> 6;
    int lane = tid & 63;
    int m = lane & 15, quad = lane >> 4;
    int n0 = blockIdx.x * 64;

    // ---- phase 1: wave w stages rows n0 + w*16 .. +15, coalesced ----
#pragma unroll 4
    for (int r = 0; r < 16; r++) {
        int row = wave * 16 + r;
        int grow = n0 + row; if (grow >= NNODES) grow = NNODES - 1;  // clamp; stores guarded
        const float* xp = X + (size_t)grow * F_IN;
        int sw = (row & 7) << 4;                 // row&7 == r&7 (wave*16 multiple of 16)
        char* lrow = (char*)&A_lds[row][0];

        // chunk 0: cols 4*lane .. +4   (covers cols 0..255)
        float4 v0 = *(const float4*)(xp + lane * 4);
        unsigned p0 = (unsigned)f2bf(v0.x) | ((unsigned)f2bf(v0.y) << 16);
        unsigned p1 = (unsigned)f2bf(v0.z) | ((unsigned)f2bf(v0.w) << 16);
        *(uint2*)(lrow + ((lane * 8) ^ sw)) = make_uint2(p0, p1);

        // chunk 1: cols 256 + 4*lane (lanes 0..60 cover cols 256..499)
        if (lane < 61) {
            float4 v1 = *(const float4*)(xp + 256 + lane * 4);
            unsigned q0 = (unsigned)f2bf(v1.x) | ((unsigned)f2bf(v1.y) << 16);
            unsigned q1 = (unsigned)f2bf(v1.z) | ((unsigned)f2bf(v1.w) << 16);
            *(uint2*)(lrow + ((512 + lane * 8) ^ sw)) = make_uint2(q0, q1);
        }
        // zero pad cols 500..511 (bytes 1000..1023) so K=15 step is clean
        if (lane < 6) {
            *(unsigned*)(lrow + ((1000 + lane * 4) ^ sw)) = 0u;
        }
    }
    __syncthreads();

    // ---- phase 2: MFMA k-loop, A from swizzled LDS, B from L2 ----
    f32x4 acc[4];
#pragma unroll
    for (int c = 0; c < 4; c++) { f32x4 z = {0.f, 0.f, 0.f, 0.f}; acc[c] = z; }

    int arow = wave * 16 + m;                    // LDS row this lane consumes
    const char* lra = (const char*)&A_lds[arow][0];
    int swr = (m & 7) << 4;

#pragma unroll 4
    for (int ks = 0; ks < KPAD / 32; ks++) {
        short8 a = *(const short8*)(lra + ((ks * 64 + quad * 16) ^ swr));
#pragma unroll
        for (int c = 0; c < 4; c++) {
            short8 b = *(const short8*)&W1T[(size_t)(c * 16 + m) * KPAD + ks * 32 + quad * 8];
            acc[c] = __builtin_amdgcn_mfma_f32_16x16x32_bf16(a, b, acc[c], 0, 0, 0);
        }
    }

    int n0w = n0 + wave * 16;
#pragma unroll
    for (int reg = 0; reg < 4; reg++) {
        int gr = n0w + quad * 4 + reg;
        if (gr < NNODES) {
            float sc = dinv[gr];
#pragma unroll
            for (int c = 0; c < 4; c++)
                h1b[(size_t)gr * F_MID + c * 16 + m] = f2bf(acc[c][reg] * sc);
        }
    }
}

// ---------------------------------------------------------------------------
// agg1: 4 nodes per 256-thread block, one wave per node, lane = feature.
// ---------------------------------------------------------------------------
__global__ __launch_bounds__(256) void agg1_kernel(const unsigned short* __restrict__ h1b,
                                                   const int* __restrict__ csr_src,
                                                   const int* __restrict__ row_start,
                                                   const float* __restrict__ dinv,
                                                   const float* __restrict__ b1,
                                                   unsigned short* __restrict__ out1b) {
    int tid = threadIdx.x;
    int node = blockIdx.x * 4 + (tid >> 6);
    int lane = tid & 63;

    int s0 = row_start[node], s1 = row_start[node + 1];
    float acc = 0.f;

    int idx[8];
    int e = s0;
#pragma unroll
    for (int j = 0; j < 8; j++) {
        int p = e + j; if (p > s1 - 1) p = s1 - 1;
        idx[j] = csr_src[p];          // uniform address -> scalar load
    }
    while (e < s1) {
        int cnt = s1 - e;             // >= 1, wave-uniform
        int cidx[8];
#pragma unroll
        for (int j = 0; j < 8; j++) cidx[j] = idx[j];
        int en = e + 8;
        if (en < s1) {
#pragma unroll
            for (int j = 0; j < 8; j++) {
                int p = en + j; if (p > s1 - 1) p = s1 - 1;
                idx[j] = csr_src[p];  // prefetch next batch (scalar)
            }
        }
#pragma unroll
        for (int j = 0; j < 8; j++) {
            float v = bf2f(h1b[(size_t)cidx[j] * F_MID + lane]);
            if (j < cnt) acc += v;    // wave-uniform predicate
        }
        e = en;
    }

    float dn = dinv[node];
    float v = fmaxf(acc * dn + b1[lane], 0.f);
    out1b[(size_t)node * F_MID + lane] = f2bf(v);
}

// ---------------------------------------------------------------------------
// GEMM2 (bf16 MFMA, no LDS): h2b[100000,48](bf16) = (out1 @ W2pad) * dinv[row]
// ---------------------------------------------------------------------------
__global__ __launch_bounds__(256) void gemm2_kernel(const unsigned short* __restrict__ out1b,
                                                    const unsigned short* __restrict__ W2T,
                                                    const float* __restrict__ dinv,
                                                    unsigned short* __restrict__ h2b) {
    int tid = threadIdx.x;
    int wave = tid >> 6;
    int lane = tid & 63;
    int n0 = blockIdx.x * 64 + wave * 16;     // 16 nodes per wave
    int m = lane & 15, quad = lane >> 4;

    int arow = n0 + m; if (arow >= NNODES) arow = NNODES - 1;

    f32x4 acc[3];
#pragma unroll
    for (int c = 0; c < 3; c++) { f32x4 z = {0.f, 0.f, 0.f, 0.f}; acc[c] = z; }

#pragma unroll
    for (int t = 0; t < 2; t++) {
        short8 a = *(const short8*)&out1b[(size_t)arow * F_MID + t * 32 + quad * 8];
#pragma unroll
        for (int c = 0; c < 3; c++) {
            short8 b = *(const short8*)&W2T[(size_t)(c * 16 + m) * F_MID + t * 32 + quad * 8];
            acc[c] = __builtin_amdgcn_mfma_f32_16x16x32_bf16(a, b, acc[c], 0, 0, 0);
        }
    }

#pragma unroll
    for (int reg = 0; reg < 4; reg++) {
        int gr = n0 + quad * 4 + reg;
        if (gr < NNODES) {
            float dn = dinv[gr];
#pragma unroll
            for (int c = 0; c < 3; c++)
                h2b[(size_t)gr * H2S + c * 16 + m] = f2bf(acc[c][reg] * dn);
        }
    }
}

// ---------------------------------------------------------------------------
// agg2 + bias + log_softmax: 4 nodes/block, lane = class.
// ---------------------------------------------------------------------------
__global__ __launch_bounds__(256) void agg2_softmax_kernel(const unsigned short* __restrict__ h2b,
                                                           const int* __restrict__ csr_src,
                                                           const int* __restrict__ row_start,
                                                           const float* __restrict__ dinv,
                                                           const float* __restrict__ b2,
                                                           float* __restrict__ out) {
    int tid = threadIdx.x;
    int node = blockIdx.x * 4 + (tid >> 6);
    int lane = tid & 63;
    int cl = (lane < H2S) ? lane : 0;

    int s0 = row_start[node], s1 = row_start[node + 1];
    float acc = 0.f;

    int idx[8];
    int e = s0;
#pragma unroll
    for (int j = 0; j < 8; j++) {
        int p = e + j; if (p > s1 - 1) p = s1 - 1;
        idx[j] = csr_src[p];
    }
    while (e < s1) {
        int cnt = s1 - e;
        int cidx[8];
#pragma unroll
        for (int j = 0; j < 8; j++) cidx[j] = idx[j];
        int en = e + 8;
        if (en < s1) {
#pragma unroll
            for (int j = 0; j < 8; j++) {
                int p = en + j; if (p > s1 - 1) p = s1 - 1;
                idx[j] = csr_src[p];
            }
        }
#pragma unroll
        for (int j = 0; j < 8; j++) {
            float v = bf2f(h2b[(size_t)cidx[j] * H2S + cl]);
            if (j < cnt) acc += v;
        }
        e = en;
    }

    float dn = dinv[node];
    bool act = (lane < F_OUT);
    float z = act ? (acc * dn + b2[cl]) : -3.4e38f;
    float m = z;
#pragma unroll
    for (int off = 1; off < 64; off <<= 1) m = fmaxf(m, __shfl_xor(m, off, 64));
    float p = act ? __expf(z - m) : 0.f;
#pragma unroll
    for (int off = 1; off < 64; off <<= 1) p += __shfl_xor(p, off, 64);
    float lse = m + logf(p);
    if (act) out[(size_t)node * F_OUT + lane] = z - lse;
}

// ---------------------------------------------------------------------------
extern "C" void kernel_launch(void* const* d_in, const int* in_sizes, int n_in,
                              void* d_out, int out_size, void* d_ws, size_t ws_size,
                              hipStream_t stream) {
    const float* X   = (const float*)d_in[0];
    const int*   ei  = (const int*)d_in[1];
    const float* W1  = (const float*)d_in[2];
    const float* b1  = (const float*)d_in[3];
    const float* W2  = (const float*)d_in[4];
    const float* b2  = (const float*)d_in[5];
    float* out = (float*)d_out;

    const int N = NNODES;
    const int E = in_sizes[1] / 2;      // 1,600,000
    const int TOTAL = E + N;
    const int* srcv = ei;
    const int* dstv = ei + E;

    char* p = (char*)d_ws;
    auto carve = [&](size_t bytes) {
        void* r = (void*)p;
        p += (bytes + 255) & ~(size_t)255;
        return r;
    };
    int*   bcnt      = (int*)carve((size_t)NBUCK * 4);
    int*   bstart    = (int*)carve((size_t)(NBUCK + 1) * 4);
    int*   bcur      = (int*)carve((size_t)NBUCK * 4);
    int*   stage     = (int*)carve((size_t)E * 4);
    int*   row_start = (int*)carve((size_t)(N + 1) * 4);
    int*   csr_src   = (int*)carve((size_t)TOTAL * 4);
    float* dinv      = (float*)carve((size_t)N * 4);
    unsigned short* W1T  = (unsigned short*)carve((size_t)F_MID * KPAD * 2);
    unsigned short* W2T  = (unsigned short*)carve((size_t)H2S * F_MID * 2);
    unsigned short* h1b  = (unsigned short*)carve((size_t)N * F_MID * 2);
    unsigned short* out1b= (unsigned short*)carve((size_t)N * F_MID * 2);
    unsigned short* h2b  = (unsigned short*)carve((size_t)N * H2S * 2);
    (void)ws_size; (void)n_in; (void)out_size;

    const int GB = (E + EPB - 1) / EPB;   // 196

    hipMemsetAsync(bcnt, 0, (size_t)NBUCK * 4, stream);
    bucket_count<<<GB, 256, 0, stream>>>(dstv, bcnt, E);
    bucket_scan<<<1, 1024, 0, stream>>>(bcnt, bstart, bcur, E);
    bucket_scatter<<<GB, 256, 0, stream>>>(srcv, dstv, bcur, stage, E);
    bucket_fill<<<NBUCK, 256, 0, stream>>>(stage, bstart, row_start, dinv, csr_src, E);

    w1t_prep<<<(F_MID * KPAD + 255) / 256, 256, 0, stream>>>(W1, W1T);
    w2t_prep<<<(H2S * F_MID + 255) / 256, 256, 0, stream>>>(W2, W2T);

    gemm1_kernel<<<(N + 63) / 64, 256, 0, stream>>>(X, W1T, dinv, h1b);
    agg1_kernel<<<N / 4, 256, 0, stream>>>(h1b, csr_src, row_start, dinv, b1, out1b);
    gemm2_kernel<<<(N + 63) / 64, 256, 0, stream>>>(out1b, W2T, dinv, h2b);
    agg2_softmax_kernel<<<N / 4, 256, 0, stream>>>(h2b, csr_src, row_start, dinv, b2, out);
}

// Round 4
// 512.683 us; speedup vs baseline: 1.0970x; 1.0970x over previous
//
#include <hip/hip_runtime.h>
#include <hip/hip_bf16.h>
#include <math.h>

// Problem constants (from reference setup_inputs)
#define NNODES 100000
#define F_IN   500
#define F_MID  64
#define F_OUT  40
#define KPAD   512     // F_IN padded to multiple of 32 for MFMA
#define H2S    48      // h2 row stride (40 classes + 8 zero pad cols)

// Bucketed CSR build: 128 nodes per bucket
#define BSH    7
#define NBUCK  782     // ceil(100000 / 128)
#define EPB    8192    // edges per block in bucket kernels
#define K4CACHE 3072   // LDS edge cache per bucket (mean 2046, +20 sigma)

typedef __attribute__((ext_vector_type(8))) short short8;   // 8 bf16 = 4 VGPRs
typedef __attribute__((ext_vector_type(4))) float f32x4;    // MFMA acc

__device__ __forceinline__ unsigned short f2bf(float f) {
    union { float f; unsigned u; } c; c.f = f;
    unsigned r = c.u + 0x7FFF + ((c.u >> 16) & 1);   // round-nearest-even
    return (unsigned short)(r >> 16);
}
__device__ __forceinline__ float bf2f(unsigned short u) {
    union { unsigned v; float f; } c; c.v = ((unsigned)u) << 16; return c.f;
}

// ---------------------------------------------------------------------------
// CSR build, two-level bucket sort. All per-edge atomics are LDS-local;
// device atomics only per (tile,bucket) reservation (~150k non-hot).
// ---------------------------------------------------------------------------

// K1: per-bucket edge counts. LDS histogram, one device atomic per
// (block,bucket) with nonzero count.
__global__ __launch_bounds__(256) void bucket_count(const int* __restrict__ dst,
                                                    int* __restrict__ bcnt, int E) {
    __shared__ int h[NBUCK];
    int tid = threadIdx.x;
    for (int b = tid; b < NBUCK; b += 256) h[b] = 0;
    __syncthreads();
    int base = blockIdx.x * EPB;
#pragma unroll
    for (int j = 0; j < EPB / 256; j++) {
        int e = base + j * 256 + tid;
        if (e < E) atomicAdd(&h[dst[e] >> BSH], 1);
    }
    __syncthreads();
    for (int b = tid; b < NBUCK; b += 256) {
        int c = h[b];
        if (c) atomicAdd(&bcnt[b], c);
    }
}

// K2: exclusive scan of the 782 bucket counts (single block).
__global__ __launch_bounds__(1024) void bucket_scan(const int* __restrict__ bcnt,
                                                    int* __restrict__ bstart,
                                                    int* __restrict__ bcur, int E) {
    __shared__ int wsum[16];
    int t = threadIdx.x, lane = t & 63, w = t >> 6;
    int v = (t < NBUCK) ? bcnt[t] : 0;
    int s = v;
#pragma unroll
    for (int off = 1; off < 64; off <<= 1) {
        int u = __shfl_up(s, off, 64);
        if (lane >= off) s += u;
    }
    if (lane == 63) wsum[w] = s;
    __syncthreads();
    if (w == 0) {
        int ws = (lane < 16) ? wsum[lane] : 0;
#pragma unroll
        for (int off = 1; off < 16; off <<= 1) {
            int u = __shfl_up(ws, off, 64);
            if (lane >= off) ws += u;
        }
        if (lane < 16) wsum[lane] = ws;
    }
    __syncthreads();
    int excl = s - v + ((w > 0) ? wsum[w - 1] : 0);
    if (t < NBUCK) { bstart[t] = excl; bcur[t] = excl; }
    if (t == 0) bstart[NBUCK] = E;
}

// K3: scatter edges into bucket-contiguous staging. One returning device
// atomic per (block,bucket); per-edge ranks via LDS atomics. Payload packed
// as (local_node << 17) | src  (src < 2^17, local_node < 128).
__global__ __launch_bounds__(256) void bucket_scatter(const int* __restrict__ src,
                                                      const int* __restrict__ dst,
                                                      int* __restrict__ bcur,
                                                      int* __restrict__ stage, int E) {
    __shared__ int h[NBUCK];
    __shared__ int lcur[NBUCK];
    int tid = threadIdx.x;
    for (int b = tid; b < NBUCK; b += 256) h[b] = 0;
    __syncthreads();
    int base = blockIdx.x * EPB;
#pragma unroll
    for (int j = 0; j < EPB / 256; j++) {
        int e = base + j * 256 + tid;
        if (e < E) atomicAdd(&h[dst[e] >> BSH], 1);
    }
    __syncthreads();
    // Rotate flush order per block so concurrent blocks hit different
    // cache lines of bcur (reduces same-line atomic serialization).
    int rot = (blockIdx.x * 97) % NBUCK;
    for (int i = tid; i < NBUCK; i += 256) {
        int b = i + rot; if (b >= NBUCK) b -= NBUCK;
        int c = h[b];
        lcur[b] = c ? atomicAdd(&bcur[b], c) : 0;
    }
    __syncthreads();
#pragma unroll
    for (int j = 0; j < EPB / 256; j++) {
        int e = base + j * 256 + tid;
        if (e < E) {
            int d = dst[e];
            int pos = atomicAdd(&lcur[d >> BSH], 1);
            stage[pos] = ((d & 127) << 17) | src[e];
        }
    }
}

// K4: one block per bucket. LDS node histogram -> local scan (+1 self-loop
// per node) gives row_start analytically; LDS cursors scatter edges into a
// contiguous ~8.6KB csr window. Also writes dinv and self-loop entries.
__global__ __launch_bounds__(256) void bucket_fill(const int* __restrict__ stage,
                                                   const int* __restrict__ bstart,
                                                   int* __restrict__ row_start,
                                                   float* __restrict__ dinv,
                                                   int* __restrict__ csr_src, int E) {
    __shared__ int cnt[128];
    __shared__ int wtot[2];
    __shared__ int cache[K4CACHE];
    int tid = threadIdx.x;
    int b = blockIdx.x;
    int s0 = bstart[b], s1 = bstart[b + 1];
    int nE = s1 - s0;
    if (tid < 128) cnt[tid] = 0;
    __syncthreads();
    bool cached = (nE <= K4CACHE);
    for (int i = tid; i < nE; i += 256) {
        int v = stage[s0 + i];
        if (cached) cache[i] = v;
        atomicAdd(&cnt[v >> 17], 1);
    }
    __syncthreads();
    int n = (b << BSH) + tid;
    bool valid = (tid < 128) && (n < NNODES);
    int c = (tid < 128) ? cnt[tid] : 0;
    int add = valid ? (c + 1) : 0;        // +1 self-loop per valid node
    int s = add;
    int lane = tid & 63;
#pragma unroll
    for (int off = 1; off < 64; off <<= 1) {
        int u = __shfl_up(s, off, 64);
        if (lane >= off) s += u;
    }
    if (tid < 128 && lane == 63) wtot[tid >> 6] = s;
    __syncthreads();
    int excl = s - add + ((tid >= 64 && tid < 128) ? wtot[0] : 0);
    // edges before this bucket = s0; self-loops before = 128*b
    int basep = s0 + (b << BSH) + excl;
    if (valid) {
        row_start[n] = basep;
        dinv[n] = rsqrtf((float)(c + 1));
        csr_src[basep] = n;               // self-loop first
        cnt[tid] = basep + 1;             // reuse as global-position cursor
    }
    if (b == NBUCK - 1 && tid == 0) row_start[NNODES] = E + NNODES;
    __syncthreads();
    for (int i = tid; i < nE; i += 256) {
        int v = cached ? cache[i] : stage[s0 + i];
        int pos = atomicAdd(&cnt[v >> 17], 1);
        csr_src[pos] = v & 0x1FFFF;
    }
}

// ---------------------------------------------------------------------------
// W1 -> bf16, transposed, K padded: W1T[n][k], n<64, k<512
// ---------------------------------------------------------------------------
__global__ void w1t_prep(const float* __restrict__ W1, unsigned short* __restrict__ W1T) {
    int idx = blockIdx.x * blockDim.x + threadIdx.x;   // 64*512
    if (idx >= F_MID * KPAD) return;
    int n = idx >> 9;          // /512
    int k = idx & (KPAD - 1);
    float v = (k < F_IN) ? W1[k * F_MID + n] : 0.f;
    W1T[idx] = f2bf(v);
}

// W2 -> bf16, transposed, padded: W2T[col][k], col<48 (40 real), k<64
__global__ void w2t_prep(const float* __restrict__ W2, unsigned short* __restrict__ W2T) {
    int idx = blockIdx.x * blockDim.x + threadIdx.x;   // 48*64
    if (idx >= H2S * F_MID) return;
    int c = idx >> 6;
    int k = idx & 63;
    float v = (c < F_OUT) ? W2[k * F_OUT + c] : 0.f;
    W2T[idx] = f2bf(v);
}

// ---------------------------------------------------------------------------
// GEMM1 (bf16 MFMA) v4: h1b = (X @ W1) * dinv[row]
// K split into two 256-col phases -> LDS only 32KB (4 blocks/CU, 16 waves).
// Staging per phase: each wave issues 16 INDEPENDENT branch-free 1KB
// wave-loads (row r, 256 cols = bytes r*2000 + half*1024 + lane*16) into a
// register array FIRST, then packs to bf16 and writes LDS. No exec-mask
// branches anywhere on the load path (phase-1 tail lanes 61-63 use a
// per-lane address clamp + zero-select -> they write the col 500-511 pad).
// XOR swizzle (byte ^ ((row&7)<<4)) keeps MFMA fragment ds_reads conflict-
// free. Deep MLP: 16KB in flight per wave x 16 waves/CU.
// ---------------------------------------------------------------------------
__global__ __launch_bounds__(256, 4) void gemm1_kernel(const float* __restrict__ X,
                                                       const unsigned short* __restrict__ W1T,
                                                       const float* __restrict__ dinv,
                                                       unsigned short* __restrict__ h1b) {
    __shared__ __align__(16) unsigned short A_lds[64][256];   // 32 KB, swizzled

    int tid = threadIdx.x;
    int wave = tid >> 6;
    int lane = tid & 63;
    int m = lane & 15, quad = lane >> 4;
    int n0 = blockIdx.x * 64;

    f32x4 acc[4];
#pragma unroll
    for (int c = 0; c < 4; c++) { f32x4 z = {0.f, 0.f, 0.f, 0.f}; acc[c] = z; }

    int arow = wave * 16 + m;                 // LDS row this lane consumes
    const char* lra = (const char*)&A_lds[arow][0];
    int swr = (m & 7) << 4;

    // phase-1 tail handling: lanes 61-63 would read cols >= 500
    bool lvalid1 = (lane < 61);
    int boff1 = lvalid1 ? (lane * 16) : 0;    // clamped address, data zeroed

#pragma unroll
    for (int half = 0; half < 2; half++) {
        // ---- stage: wave w loads rows w*16 .. +15, cols half*256..+255 ----
        float4 v[16];
#pragma unroll
        for (int i = 0; i < 16; i++) {
            int grow = n0 + wave * 16 + i;
            if (grow >= NNODES) grow = NNODES - 1;      // clamp; stores guarded
            const char* xp = (const char*)(X + (size_t)grow * F_IN) + half * 1024;
            int boff = (half == 0) ? (lane * 16) : boff1;
            v[i] = *(const float4*)(xp + boff);
        }
#pragma unroll
        for (int i = 0; i < 16; i++) {
            int row = wave * 16 + i;
            unsigned p0 = (unsigned)f2bf(v[i].x) | ((unsigned)f2bf(v[i].y) << 16);
            unsigned p1 = (unsigned)f2bf(v[i].z) | ((unsigned)f2bf(v[i].w) << 16);
            if (half == 1 && !lvalid1) { p0 = 0u; p1 = 0u; }   // pad cols 500-511
            char* lrow = (char*)&A_lds[row][0];
            *(uint2*)(lrow + ((lane * 8) ^ ((row & 7) << 4))) = make_uint2(p0, p1);
        }
        __syncthreads();

        // ---- MFMA: 8 k-steps over this half ----
#pragma unroll
        for (int ks0 = 0; ks0 < 8; ks0++) {
            int gks = half * 8 + ks0;
            short8 a = *(const short8*)(lra + ((ks0 * 64 + quad * 16) ^ swr));
#pragma unroll
            for (int c = 0; c < 4; c++) {
                short8 b = *(const short8*)&W1T[(size_t)(c * 16 + m) * KPAD + gks * 32 + quad * 8];
                acc[c] = __builtin_amdgcn_mfma_f32_16x16x32_bf16(a, b, acc[c], 0, 0, 0);
            }
        }
        __syncthreads();   // LDS reuse: phase reads done before next overwrite
    }

    int n0w = n0 + wave * 16;
#pragma unroll
    for (int reg = 0; reg < 4; reg++) {
        int gr = n0w + quad * 4 + reg;
        if (gr < NNODES) {
            float sc = dinv[gr];
#pragma unroll
            for (int c = 0; c < 4; c++)
                h1b[(size_t)gr * F_MID + c * 16 + m] = f2bf(acc[c][reg] * sc);
        }
    }
}

// ---------------------------------------------------------------------------
// agg1: 4 nodes per 256-thread block, one wave per node, lane = feature.
// ---------------------------------------------------------------------------
__global__ __launch_bounds__(256) void agg1_kernel(const unsigned short* __restrict__ h1b,
                                                   const int* __restrict__ csr_src,
                                                   const int* __restrict__ row_start,
                                                   const float* __restrict__ dinv,
                                                   const float* __restrict__ b1,
                                                   unsigned short* __restrict__ out1b) {
    int tid = threadIdx.x;
    int node = blockIdx.x * 4 + (tid >> 6);
    int lane = tid & 63;

    int s0 = row_start[node], s1 = row_start[node + 1];
    float acc = 0.f;

    int idx[8];
    int e = s0;
#pragma unroll
    for (int j = 0; j < 8; j++) {
        int p = e + j; if (p > s1 - 1) p = s1 - 1;
        idx[j] = csr_src[p];          // uniform address -> scalar load
    }
    while (e < s1) {
        int cnt = s1 - e;             // >= 1, wave-uniform
        int cidx[8];
#pragma unroll
        for (int j = 0; j < 8; j++) cidx[j] = idx[j];
        int en = e + 8;
        if (en < s1) {
#pragma unroll
            for (int j = 0; j < 8; j++) {
                int p = en + j; if (p > s1 - 1) p = s1 - 1;
                idx[j] = csr_src[p];  // prefetch next batch (scalar)
            }
        }
#pragma unroll
        for (int j = 0; j < 8; j++) {
            float v = bf2f(h1b[(size_t)cidx[j] * F_MID + lane]);
            if (j < cnt) acc += v;    // wave-uniform predicate
        }
        e = en;
    }

    float dn = dinv[node];
    float v = fmaxf(acc * dn + b1[lane], 0.f);
    out1b[(size_t)node * F_MID + lane] = f2bf(v);
}

// ---------------------------------------------------------------------------
// GEMM2 (bf16 MFMA, no LDS): h2b[100000,48](bf16) = (out1 @ W2pad) * dinv[row]
// ---------------------------------------------------------------------------
__global__ __launch_bounds__(256) void gemm2_kernel(const unsigned short* __restrict__ out1b,
                                                    const unsigned short* __restrict__ W2T,
                                                    const float* __restrict__ dinv,
                                                    unsigned short* __restrict__ h2b) {
    int tid = threadIdx.x;
    int wave = tid >> 6;
    int lane = tid & 63;
    int n0 = blockIdx.x * 64 + wave * 16;     // 16 nodes per wave
    int m = lane & 15, quad = lane >> 4;

    int arow = n0 + m; if (arow >= NNODES) arow = NNODES - 1;

    f32x4 acc[3];
#pragma unroll
    for (int c = 0; c < 3; c++) { f32x4 z = {0.f, 0.f, 0.f, 0.f}; acc[c] = z; }

#pragma unroll
    for (int t = 0; t < 2; t++) {
        short8 a = *(const short8*)&out1b[(size_t)arow * F_MID + t * 32 + quad * 8];
#pragma unroll
        for (int c = 0; c < 3; c++) {
            short8 b = *(const short8*)&W2T[(size_t)(c * 16 + m) * F_MID + t * 32 + quad * 8];
            acc[c] = __builtin_amdgcn_mfma_f32_16x16x32_bf16(a, b, acc[c], 0, 0, 0);
        }
    }

#pragma unroll
    for (int reg = 0; reg < 4; reg++) {
        int gr = n0 + quad * 4 + reg;
        if (gr < NNODES) {
            float dn = dinv[gr];
#pragma unroll
            for (int c = 0; c < 3; c++)
                h2b[(size_t)gr * H2S + c * 16 + m] = f2bf(acc[c][reg] * dn);
        }
    }
}

// ---------------------------------------------------------------------------
// agg2 + bias + log_softmax: 4 nodes/block, lane = class.
// ---------------------------------------------------------------------------
__global__ __launch_bounds__(256) void agg2_softmax_kernel(const unsigned short* __restrict__ h2b,
                                                           const int* __restrict__ csr_src,
                                                           const int* __restrict__ row_start,
                                                           const float* __restrict__ dinv,
                                                           const float* __restrict__ b2,
                                                           float* __restrict__ out) {
    int tid = threadIdx.x;
    int node = blockIdx.x * 4 + (tid >> 6);
    int lane = tid & 63;
    int cl = (lane < H2S) ? lane : 0;

    int s0 = row_start[node], s1 = row_start[node + 1];
    float acc = 0.f;

    int idx[8];
    int e = s0;
#pragma unroll
    for (int j = 0; j < 8; j++) {
        int p = e + j; if (p > s1 - 1) p = s1 - 1;
        idx[j] = csr_src[p];
    }
    while (e < s1) {
        int cnt = s1 - e;
        int cidx[8];
#pragma unroll
        for (int j = 0; j < 8; j++) cidx[j] = idx[j];
        int en = e + 8;
        if (en < s1) {
#pragma unroll
            for (int j = 0; j < 8; j++) {
                int p = en + j; if (p > s1 - 1) p = s1 - 1;
                idx[j] = csr_src[p];
            }
        }
#pragma unroll
        for (int j = 0; j < 8; j++) {
            float v = bf2f(h2b[(size_t)cidx[j] * H2S + cl]);
            if (j < cnt) acc += v;
        }
        e = en;
    }

    float dn = dinv[node];
    bool act = (lane < F_OUT);
    float z = act ? (acc * dn + b2[cl]) : -3.4e38f;
    float m = z;
#pragma unroll
    for (int off = 1; off < 64; off <<= 1) m = fmaxf(m, __shfl_xor(m, off, 64));
    float p = act ? __expf(z - m) : 0.f;
#pragma unroll
    for (int off = 1; off < 64; off <<= 1) p += __shfl_xor(p, off, 64);
    float lse = m + logf(p);
    if (act) out[(size_t)node * F_OUT + lane] = z - lse;
}

// ---------------------------------------------------------------------------
extern "C" void kernel_launch(void* const* d_in, const int* in_sizes, int n_in,
                              void* d_out, int out_size, void* d_ws, size_t ws_size,
                              hipStream_t stream) {
    const float* X   = (const float*)d_in[0];
    const int*   ei  = (const int*)d_in[1];
    const float* W1  = (const float*)d_in[2];
    const float* b1  = (const float*)d_in[3];
    const float* W2  = (const float*)d_in[4];
    const float* b2  = (const float*)d_in[5];
    float* out = (float*)d_out;

    const int N = NNODES;
    const int E = in_sizes[1] / 2;      // 1,600,000
    const int TOTAL = E + N;
    const int* srcv = ei;
    const int* dstv = ei + E;

    char* p = (char*)d_ws;
    auto carve = [&](size_t bytes) {
        void* r = (void*)p;
        p += (bytes + 255) & ~(size_t)255;
        return r;
    };
    int*   bcnt      = (int*)carve((size_t)NBUCK * 4);
    int*   bstart    = (int*)carve((size_t)(NBUCK + 1) * 4);
    int*   bcur      = (int*)carve((size_t)NBUCK * 4);
    int*   stage     = (int*)carve((size_t)E * 4);
    int*   row_start = (int*)carve((size_t)(N + 1) * 4);
    int*   csr_src   = (int*)carve((size_t)TOTAL * 4);
    float* dinv      = (float*)carve((size_t)N * 4);
    unsigned short* W1T  = (unsigned short*)carve((size_t)F_MID * KPAD * 2);
    unsigned short* W2T  = (unsigned short*)carve((size_t)H2S * F_MID * 2);
    unsigned short* h1b  = (unsigned short*)carve((size_t)N * F_MID * 2);
    unsigned short* out1b= (unsigned short*)carve((size_t)N * F_MID * 2);
    unsigned short* h2b  = (unsigned short*)carve((size_t)N * H2S * 2);
    (void)ws_size; (void)n_in; (void)out_size;

    const int GB = (E + EPB - 1) / EPB;   // 196

    hipMemsetAsync(bcnt, 0, (size_t)NBUCK * 4, stream);
    bucket_count<<<GB, 256, 0, stream>>>(dstv, bcnt, E);
    bucket_scan<<<1, 1024, 0, stream>>>(bcnt, bstart, bcur, E);
    bucket_scatter<<<GB, 256, 0, stream>>>(srcv, dstv, bcur, stage, E);
    bucket_fill<<<NBUCK, 256, 0, stream>>>(stage, bstart, row_start, dinv, csr_src, E);

    w1t_prep<<<(F_MID * KPAD + 255) / 256, 256, 0, stream>>>(W1, W1T);
    w2t_prep<<<(H2S * F_MID + 255) / 256, 256, 0, stream>>>(W2, W2T);

    gemm1_kernel<<<(N + 63) / 64, 256, 0, stream>>>(X, W1T, dinv, h1b);
    agg1_kernel<<<N / 4, 256, 0, stream>>>(h1b, csr_src, row_start, dinv, b1, out1b);
    gemm2_kernel<<<(N + 63) / 64, 256, 0, stream>>>(out1b, W2T, dinv, h2b);
    agg2_softmax_kernel<<<N / 4, 256, 0, stream>>>(h2b, csr_src, row_start, dinv, b2, out);
}